// Round 1
// 225.197 us; speedup vs baseline: 1.0688x; 1.0688x over previous
//
#include <hip/hip_runtime.h>

typedef __attribute__((ext_vector_type(8))) short short8;
typedef __attribute__((ext_vector_type(4))) float f32x4;
typedef __attribute__((ext_vector_type(2))) float f32x2;
typedef unsigned short u16;
typedef unsigned int u32;

#define MFMA16(a, b, c) __builtin_amdgcn_mfma_f32_16x16x32_bf16((a), (b), (c), 0, 0, 0)
#define SCALE 0.044194173824159216f /* 1/sqrt(512) */

// LDS swizzles: XOR row bits into the bank-group bits so stride-4KB row
// accesses spread across banks (16-way -> <=2-way, m136/m201).
// f32 tile: 4-float (16B) granule.
#define SCX(r, c) ((c) ^ (((r) & 7) << 2))
// u16 tile: 8-u16 (16B) granule.
#define PAX(r, c) ((c) ^ (((r) & 7) << 3))

__device__ __forceinline__ u16 f2bf(float f) {
    u32 u = __float_as_uint(f);
    u = (u + 0x7fffu + ((u >> 16) & 1u)) >> 16; // RNE
    return (u16)u;
}

__global__ __launch_bounds__(256) void cvt_kernel(const float* __restrict__ src,
                                                  u16* __restrict__ dst, int n4) {
    int i = blockIdx.x * 256 + threadIdx.x;
    if (i >= n4) return;
    float4 v = ((const float4*)src)[i];
    unsigned long long p = (unsigned long long)f2bf(v.x)
                         | ((unsigned long long)f2bf(v.y) << 16)
                         | ((unsigned long long)f2bf(v.z) << 32)
                         | ((unsigned long long)f2bf(v.w) << 48);
    ((unsigned long long*)dst)[i] = p;
}

// rel[r,c] = sum_k pos_emb[r,k] * Wp[c,k] + bp[c], r<2047, c<64 -> bf16
__global__ __launch_bounds__(256) void rel_kernel(const float* __restrict__ pos_emb,
                                                  const float* __restrict__ Wp,
                                                  const float* __restrict__ bp,
                                                  u16* __restrict__ rel) {
    int idx = blockIdx.x * 256 + threadIdx.x;
    if (idx >= 2047 * 64) return;
    int r = idx >> 6, c = idx & 63;
    const float* pe = pos_emb + r * 64;
    const float* w  = Wp + c * 64;
    float acc = bp[c];
#pragma unroll
    for (int k = 0; k < 64; k++) acc += pe[k] * w[k];
    rel[r * 64 + c] = f2bf(acc);
}

// C[M,N] = A[M,K] @ B[N,K]^T, bf16 inputs, 64x64 block tile, 4 waves 2x2.
// MODE 0: q/k proj -> bf16 [B,H,S,dh], bias[n]
// MODE 1: v proj (A=Wv, B=value) -> bf16 vT [B,H,dh,S], bias[m]
// MODE 2: final   -> fp32 row-major, bias[n]
template <int MODE>
__global__ __launch_bounds__(256) void gemm_kernel(const u16* __restrict__ A,
                                                   const u16* __restrict__ B,
                                                   const float* __restrict__ bias,
                                                   void* __restrict__ Cout,
                                                   int M, int N, int K) {
    int tid = threadIdx.x;
    int w = tid >> 6, lane = tid & 63;
    int wi = w >> 1, wj = w & 1;
    int qd = lane >> 4, ln = lane & 15;
    int m_base = blockIdx.x * 64 + wi * 32;
    int n_base = blockIdx.y * 64 + wj * 32;
    f32x4 acc[2][2] = {};
    const u16* a0p = A + (long)(m_base + ln) * K + qd * 8;
    const u16* a1p = a0p + 16 * K;
    const u16* b0p = B + (long)(n_base + ln) * K + qd * 8;
    const u16* b1p = b0p + 16 * K;
    for (int kc = 0; kc < K; kc += 32) {
        short8 a0 = *(const short8*)(a0p + kc);
        short8 a1 = *(const short8*)(a1p + kc);
        short8 b0 = *(const short8*)(b0p + kc);
        short8 b1 = *(const short8*)(b1p + kc);
        acc[0][0] = MFMA16(a0, b0, acc[0][0]);
        acc[0][1] = MFMA16(a0, b1, acc[0][1]);
        acc[1][0] = MFMA16(a1, b0, acc[1][0]);
        acc[1][1] = MFMA16(a1, b1, acc[1][1]);
    }
#pragma unroll
    for (int i = 0; i < 2; i++)
#pragma unroll
        for (int j = 0; j < 2; j++)
#pragma unroll
            for (int r = 0; r < 4; r++) {
                int m = m_base + i * 16 + qd * 4 + r;
                int n = n_base + j * 16 + ln;
                float v = acc[i][j][r];
                if (MODE == 0) {
                    v += bias[n];
                    int b = m >> 10, s = m & 1023, h = n >> 6, d = n & 63;
                    ((u16*)Cout)[(((long)(b * 8 + h) << 10) + s) * 64 + d] = f2bf(v);
                } else if (MODE == 1) {
                    v += bias[m];
                    int b = n >> 10, t = n & 1023, h = m >> 6, d = m & 63;
                    ((u16*)Cout)[(((long)(b * 8 + h) * 64 + d) << 10) + t] = f2bf(v);
                } else {
                    v += bias[n];
                    ((float*)Cout)[(long)m * N + n] = v;
                }
            }
}

// One block per (b, h, 16-row s-tile). 256 threads = 4 waves.
// Phase1: content scores (f32 sc tile, swizzled). Phase2: pos scores via
// banded r-tiles + diagonal scatter. Phase3: softmax in regs; then (after a
// sync, all f32 reads complete) the attn tile is packed to bf16 ONCE via
// v_cvt_pk_bf16_f32 into a u16 LDS tile aliasing sc. Phase4: attn @ V^T
// reading MFMA A-fragments as short8 directly (no per-wave re-conversion,
// 2-way max bank conflict via PAX swizzle).
__global__ __launch_bounds__(256) void score_kernel(const u16* __restrict__ qws,
                                                    const u16* __restrict__ kws,
                                                    const u16* __restrict__ vtws,
                                                    const u16* __restrict__ relws,
                                                    float* __restrict__ out_attn,
                                                    float* __restrict__ out_cont,
                                                    float* __restrict__ out_pos,
                                                    u16* __restrict__ ctx) {
    __shared__ __align__(16) float sc[16][1024]; // exactly 64 KB
    u16* pa = (u16*)sc; // [16][1024] u16 alias; live only after phase-3 sync
    int st = blockIdx.x, h = blockIdx.y, b = blockIdx.z;
    int s0 = st * 16;
    int tid = threadIdx.x;
    int w = tid >> 6, lane = tid & 63, qd = lane >> 4, ln = lane & 15;
    int bh = b * 8 + h;

    const u16* qbase  = qws + ((long)bh << 10) * 64;   // [1024][64]
    const u16* kbase  = kws + ((long)bh << 10) * 64;   // [1024][64]
    const u16* vtbase = vtws + ((long)bh << 6) * 1024; // [64][1024]
    float* attn_base = out_attn + ((long)bh << 20) + (long)s0 * 1024;
    float* cont_base = out_cont + ((long)bh << 20) + (long)s0 * 1024;
    float* pos_base  = out_pos  + ((long)bh << 20) + (long)s0 * 1024;

    // q fragments for the 16-row s-subtile (K=64 -> two 32-chunks)
    short8 qa0 = *(const short8*)(qbase + (s0 + ln) * 64 + qd * 8);
    short8 qa1 = *(const short8*)(qbase + (s0 + ln) * 64 + 32 + qd * 8);

    // ---- Phase 1: content. Wave w covers t in [w*256, w*256+256) ----
    for (int tt = 0; tt < 16; tt++) {
        int t0 = w * 256 + tt * 16;
        short8 kb0 = *(const short8*)(kbase + (t0 + ln) * 64 + qd * 8);
        short8 kb1 = *(const short8*)(kbase + (t0 + ln) * 64 + 32 + qd * 8);
        f32x4 acc = {};
        acc = MFMA16(qa0, kb0, acc);
        acc = MFMA16(qa1, kb1, acc);
#pragma unroll
        for (int r = 0; r < 4; r++) {
            int sl = qd * 4 + r;
            int t = t0 + ln;
            cont_base[sl * 1024 + t] = acc[r];
            sc[sl][SCX(sl, t)] = acc[r] * SCALE;
        }
    }
    __syncthreads();

    // ---- Phase 2: pos. r in [1008-s0, 1008-s0+1040), 65 r-subtiles ----
    int rbase = 1008 - s0;
    for (int rt = w; rt < 65; rt += 4) {
        int r0 = rbase + rt * 16;
        short8 rb0 = *(const short8*)(relws + (r0 + ln) * 64 + qd * 8);
        short8 rb1 = *(const short8*)(relws + (r0 + ln) * 64 + 32 + qd * 8);
        f32x4 acc = {};
        acc = MFMA16(qa0, rb0, acc);
        acc = MFMA16(qa1, rb1, acc);
#pragma unroll
        for (int r = 0; r < 4; r++) {
            int sl = qd * 4 + r;
            int t = rt * 16 + ln + sl - 15; // = r - 1023 + s  (s0 cancels)
            if (t >= 0 && t < 1024) {
                pos_base[sl * 1024 + t] = acc[r];
                sc[sl][SCX(sl, t)] += acc[r] * SCALE;
            }
        }
    }
    __syncthreads();

    // ---- Phase 3: softmax. 16 threads per row; each owns 32 adjacent
    //      col-PAIRS (2g+32i, +1) -> float2 reads, shuffle-free bf16 pack.
    {
        int row = tid >> 4;
        int g = tid & 15;
        float ev[64];
        float mx = -1e30f;
#pragma unroll
        for (int i = 0; i < 32; i++) {
            int c = 2 * g + 32 * i;
            f32x2 v = *(const f32x2*)&sc[row][SCX(row, c)];
            ev[2 * i] = v[0];
            ev[2 * i + 1] = v[1];
            mx = fmaxf(mx, fmaxf(v[0], v[1]));
        }
        for (int off = 1; off < 16; off <<= 1) mx = fmaxf(mx, __shfl_xor(mx, off, 64));
        float sum = 0.f;
#pragma unroll
        for (int i = 0; i < 64; i++) {
            float e = __expf(ev[i] - mx);
            ev[i] = e;
            sum += e;
        }
        for (int off = 1; off < 16; off <<= 1) sum += __shfl_xor(sum, off, 64);
        float inv = 1.0f / sum;
        __syncthreads(); // every thread's sc reads are in regs; pa may now clobber sc
#pragma unroll
        for (int i = 0; i < 32; i++) {
            int c = 2 * g + 32 * i;
            float a0 = ev[2 * i] * inv;
            float a1 = ev[2 * i + 1] * inv;
            f32x2 av = {a0, a1};
            *(f32x2*)&attn_base[row * 1024 + c] = av;
            u32 pk;
            asm("v_cvt_pk_bf16_f32 %0, %1, %2" : "=v"(pk) : "v"(a0), "v"(a1));
            *(u32*)&pa[row * 1024 + PAX(row, c)] = pk;
        }
    }
    __syncthreads();

    // ---- Phase 4: o = attn @ v. Wave w -> d-subtile [w*16, w*16+16).
    //      A-fragment read straight from the packed bf16 tile. ----
    {
        const u16* vrow = vtbase + (w * 16 + ln) * 1024 + qd * 8;
        f32x4 oacc = {};
        for (int kt = 0; kt < 32; kt++) {
            int c = kt * 32 + qd * 8;
            short8 a = *(const short8*)&pa[ln * 1024 + PAX(ln, c)];
            short8 bf = *(const short8*)(vrow + kt * 32);
            oacc = MFMA16(a, bf, oacc);
        }
#pragma unroll
        for (int r = 0; r < 4; r++) {
            int sl = qd * 4 + r;
            int d = w * 16 + ln;
            ctx[((long)(b * 1024 + s0 + sl)) * 512 + h * 64 + d] = f2bf(oacc[r]);
        }
    }
}

extern "C" void kernel_launch(void* const* d_in, const int* in_sizes, int n_in,
                              void* d_out, int out_size, void* d_ws, size_t ws_size,
                              hipStream_t stream) {
    (void)in_sizes; (void)n_in; (void)out_size; (void)ws_size;
    const float* query   = (const float*)d_in[0];
    const float* key     = (const float*)d_in[1];
    const float* value   = (const float*)d_in[2];
    const float* pos_emb = (const float*)d_in[3];
    const float* Wq = (const float*)d_in[4];
    const float* bq = (const float*)d_in[5];
    const float* Wk = (const float*)d_in[6];
    const float* bk = (const float*)d_in[7];
    const float* Wv = (const float*)d_in[8];
    const float* bv = (const float*)d_in[9];
    const float* Wo = (const float*)d_in[10];
    const float* bo = (const float*)d_in[11];
    const float* Wp = (const float*)d_in[12];
    const float* bp = (const float*)d_in[13];

    // workspace layout (bf16 u16 elements)
    u16* qin  = (u16*)d_ws;            // 4096*512
    u16* kin  = qin + 4096 * 512;
    u16* vin  = kin + 4096 * 512;
    u16* wqb  = vin + 4096 * 512;      // 512*512 each
    u16* wkb  = wqb + 512 * 512;
    u16* wvb  = wkb + 512 * 512;
    u16* wob  = wvb + 512 * 512;
    u16* relb = wob + 512 * 512;       // 2048*64 (row 2047 read-garbage, discarded)
    u16* qws  = relb + 2048 * 64;      // [B,H,S,64]
    u16* kws  = qws + 4 * 8 * 1024 * 64;
    u16* vtws = kws + 4 * 8 * 1024 * 64; // [B,H,64,S]
    u16* ctx  = qin; // alias: qin dead after q-projection

    float* out  = (float*)d_out;
    float* attn = out + 2097152;
    float* cont = attn + 33554432;
    float* pos  = cont + 33554432;

    cvt_kernel<<<2048, 256, 0, stream>>>(query, qin, 524288);
    cvt_kernel<<<2048, 256, 0, stream>>>(key, kin, 524288);
    cvt_kernel<<<2048, 256, 0, stream>>>(value, vin, 524288);
    cvt_kernel<<<256, 256, 0, stream>>>(Wq, wqb, 65536);
    cvt_kernel<<<256, 256, 0, stream>>>(Wk, wkb, 65536);
    cvt_kernel<<<256, 256, 0, stream>>>(Wv, wvb, 65536);
    cvt_kernel<<<256, 256, 0, stream>>>(Wo, wob, 65536);
    rel_kernel<<<512, 256, 0, stream>>>(pos_emb, Wp, bp, relb);

    gemm_kernel<0><<<dim3(64, 8), 256, 0, stream>>>(qin, wqb, bq, qws, 4096, 512, 512);
    gemm_kernel<0><<<dim3(64, 8), 256, 0, stream>>>(kin, wkb, bk, kws, 4096, 512, 512);
    gemm_kernel<1><<<dim3(8, 64), 256, 0, stream>>>(wvb, vin, bv, vtws, 512, 4096, 512);

    score_kernel<<<dim3(64, 8, 4), 256, 0, stream>>>(qws, kws, vtws, relb, attn, cont, pos, ctx);

    gemm_kernel<2><<<dim3(64, 8), 256, 0, stream>>>(ctx, wob, bo, out, 4096, 512, 512);
}